// Round 5
// baseline (165.921 us; speedup 1.0000x reference)
//
#include <hip/hip_runtime.h>
#include <cstdint>
#include <cstddef>

#define B 128
#define P 8732
#define NC 21
#define O 16
#define THRESH 0.5f
#define HP 4366   // P/2 prior-pairs per image

typedef unsigned long long u64;
typedef unsigned int u32;
typedef unsigned char u8;

__device__ __forceinline__ float iou_pt(float a0, float a1, float a2, float a3,
                                        float b0, float b1, float b2, float b3) {
    float ltx = fmaxf(a0, b0), lty = fmaxf(a1, b1);
    float rbx = fminf(a2, b2), rby = fminf(a3, b3);
    float wx = fmaxf(rbx - ltx, 0.0f), wy = fmaxf(rby - lty, 0.0f);
    float inter = wx * wy;
    float aa = (a2 - a0) * (a3 - a1);
    float ab = (b2 - b0) * (b3 - b1);
    return inter / (aa + ab - inter);
}

// Pass 1: per-object best prior (u64-key max reduce) AND, optionally, the
// per-prior best-truth (ov float + idx u8) stored exactly for pass2.
__global__ void __launch_bounds__(256) k_pass1(const float* __restrict__ gt,
                                               const float* __restrict__ priors,
                                               u64* __restrict__ bestkey,
                                               float* __restrict__ bestov,
                                               u8* __restrict__ bestidx) {
    const int b = blockIdx.y;
    __shared__ float s_gt[O * 4];
    __shared__ u64 s_wk[4][O];
    const int tid = threadIdx.x;
    const int wave = tid >> 6, lane = tid & 63;
    if (tid < O * 4) {
        int o = tid >> 2, c = tid & 3;
        s_gt[tid] = gt[(b * O + o) * 5 + c];
    }
    __syncthreads();

    u64 lk[O];
#pragma unroll
    for (int o = 0; o < O; o++) lk[o] = 0ull;

    for (int p = blockIdx.x * 256 + tid; p < P; p += 2048) {
        float4 pr = reinterpret_cast<const float4*>(priors)[p];
        float b0 = pr.x - pr.z * 0.5f, b1 = pr.y - pr.w * 0.5f;
        float b2 = pr.x + pr.z * 0.5f, b3 = pr.y + pr.w * 0.5f;
        float bov = -1.0f; int bidx = 0;
#pragma unroll
        for (int o = 0; o < O; o++) {
            float v = iou_pt(s_gt[o * 4 + 0], s_gt[o * 4 + 1], s_gt[o * 4 + 2], s_gt[o * 4 + 3],
                             b0, b1, b2, b3);
            u64 key = ((u64)__float_as_uint(v) << 32) | (u64)(0xFFFFFFFFu - (u32)p);
            lk[o] = (key > lk[o]) ? key : lk[o];
            if (v > bov) { bov = v; bidx = o; }   // first occurrence on tie
        }
        if (bestov) {
            bestov[(size_t)b * P + p] = bov;
            bestidx[(size_t)b * P + p] = (u8)bidx;
        }
    }

#pragma unroll
    for (int o = 0; o < O; o++) {
        u64 k = lk[o];
#pragma unroll
        for (int off = 32; off > 0; off >>= 1) {
            u64 other = (u64)__shfl_xor((long long)k, off, 64);
            k = (other > k) ? other : k;
        }
        if (lane == 0) s_wk[wave][o] = k;
    }
    __syncthreads();
    if (tid < O) {
        u64 k = s_wk[0][tid];
#pragma unroll
        for (int w = 1; w < 4; w++) { u64 v = s_wk[w][tid]; k = (v > k) ? v : k; }
        atomicMax(&bestkey[b * O + tid], k);
    }
}

// Per-prior softmax-CE / smooth-L1 body. J is a compile-time prior-in-pair
// index so every fs[] access is a static register index (no scratch).
template<int J>
__device__ __forceinline__ void prior_body(const float (&fs)[42], const float* s_gt,
                                           const int* s_bp, float4 pr, int p0,
                                           float pov, int pidx,
                                           const float* __restrict__ loc_preds,
                                           size_t lp_base, float& mine_v,
                                           float& l_loc, float& l_ce, int& l_np) {
#pragma unroll
    for (int o = 0; o < O; o++)
        if (s_bp[o] == p0 + J) { pidx = o; pov = 2.0f; }   // ascending: last wins
    int cls = (pov < THRESH) ? 0 : (int)s_gt[pidx * 5 + 4];

    // max over 21 (tree, depth ~5)
    float t[11];
#pragma unroll
    for (int i = 0; i < 10; i++) t[i] = fmaxf(fs[21 * J + 2 * i], fs[21 * J + 2 * i + 1]);
    t[10] = fs[21 * J + 20];
#pragma unroll
    for (int s = 11; s > 1; s = (s + 1) >> 1) {
#pragma unroll
        for (int i = 0; i < (s >> 1); i++) t[i] = fmaxf(t[i], t[s - 1 - i]);
    }
    float mx = t[0];

    float se0 = 0.f, se1 = 0.f, se2 = 0.f, se3 = 0.f;
#pragma unroll
    for (int c = 0; c < 20; c += 4) {
        se0 += __expf(fs[21 * J + c + 0] - mx);
        se1 += __expf(fs[21 * J + c + 1] - mx);
        se2 += __expf(fs[21 * J + c + 2] - mx);
        se3 += __expf(fs[21 * J + c + 3] - mx);
    }
    se0 += __expf(fs[21 * J + 20] - mx);
    float lse = mx + __logf((se0 + se1) + (se2 + se3));

    // gather fs[cls] as a sum-of-selects tree (exact: exactly one term nonzero)
    float g0 = 0.f, g1 = 0.f, g2 = 0.f, g3 = 0.f;
#pragma unroll
    for (int c = 0; c < 20; c += 4) {
        g0 += (c + 0 == cls) ? fs[21 * J + c + 0] : 0.0f;
        g1 += (c + 1 == cls) ? fs[21 * J + c + 1] : 0.0f;
        g2 += (c + 2 == cls) ? fs[21 * J + c + 2] : 0.0f;
        g3 += (c + 3 == cls) ? fs[21 * J + c + 3] : 0.0f;
    }
    g0 += (20 == cls) ? fs[21 * J + 20] : 0.0f;
    float ce = lse - ((g0 + g1) + (g2 + g3));

    bool pos = cls > 0;
    mine_v = pos ? 0.0f : ce;

    if (pos) {
        l_np++;
        l_ce += ce;
        float m0 = s_gt[pidx * 5 + 0], m1 = s_gt[pidx * 5 + 1];
        float m2 = s_gt[pidx * 5 + 2], m3 = s_gt[pidx * 5 + 3];
        float tx = ((m0 + m2) * 0.5f - pr.x) / (0.1f * pr.z);
        float ty = ((m1 + m3) * 0.5f - pr.y) / (0.1f * pr.w);
        float tw = __logf((m2 - m0) / pr.z) * 5.0f;
        float th = __logf((m3 - m1) / pr.w) * 5.0f;
        float4 lp = reinterpret_cast<const float4*>(loc_preds)[lp_base + p0 + J];
        float d0 = fabsf(lp.x - tx), d1 = fabsf(lp.y - ty);
        float d2 = fabsf(lp.z - tw), d3 = fabsf(lp.w - th);
        float s0 = d0 < 1.0f ? 0.5f * d0 * d0 : d0 - 0.5f;
        float s1 = d1 < 1.0f ? 0.5f * d1 * d1 : d1 - 0.5f;
        float s2 = d2 < 1.0f ? 0.5f * d2 * d2 : d2 - 0.5f;
        float s3 = d3 < 1.0f ? 0.5f * d3 * d3 : d3 - 0.5f;
        l_loc += (s0 + s1) + (s2 + s3);
    }
}

// Pass 2: 2 priors/thread, 21 independent float2 score loads.
template<bool PRE>
__global__ void __launch_bounds__(256) k_pass2(const float* __restrict__ gt,
                                               const float* __restrict__ priors,
                                               const u64* __restrict__ bestkey,
                                               const float* __restrict__ loc_preds,
                                               const float* __restrict__ scores,
                                               const float* __restrict__ bestov,
                                               const u8* __restrict__ bestidx,
                                               float* __restrict__ mine,
                                               int* __restrict__ num_pos,
                                               u32* __restrict__ total_pos,
                                               double* __restrict__ acc) {
    const int b = blockIdx.y;
    __shared__ float s_gt[O * 5];
    __shared__ int s_bp[O];
    const int tid = threadIdx.x;
    if (tid < O * 5) s_gt[tid] = gt[b * O * 5 + tid];
    if (tid < O) s_bp[tid] = (int)(0xFFFFFFFFu - (u32)(bestkey[b * O + tid] & 0xFFFFFFFFull));
    __syncthreads();

    const int t = blockIdx.x * 256 + tid;   // pair index
    float l_loc = 0.f, l_ce = 0.f;
    int l_np = 0;

    if (t < HP) {
        const int p0 = 2 * t;
        float fs[42];
        const float2* s2 = reinterpret_cast<const float2*>(scores)
                           + (size_t)b * (size_t)(P * NC / 2) + (size_t)21 * t;
#pragma unroll
        for (int i = 0; i < 21; i++) {
            float2 v = s2[i];
            fs[2 * i] = v.x; fs[2 * i + 1] = v.y;
        }
        float4 pr0 = reinterpret_cast<const float4*>(priors)[p0];
        float4 pr1 = reinterpret_cast<const float4*>(priors)[p0 + 1];

        float ov0, ov1; int id0, id1;
        if (PRE) {
            float2 ovp = reinterpret_cast<const float2*>(bestov)[(size_t)b * HP + t];
            ov0 = ovp.x; ov1 = ovp.y;
            unsigned short w = *reinterpret_cast<const unsigned short*>(bestidx + (size_t)b * P + p0);
            id0 = w & 255; id1 = w >> 8;
        } else {
            float pb0, pb1, pb2, pb3;
            ov0 = -1.0f; id0 = 0;
            pb0 = pr0.x - pr0.z * 0.5f; pb1 = pr0.y - pr0.w * 0.5f;
            pb2 = pr0.x + pr0.z * 0.5f; pb3 = pr0.y + pr0.w * 0.5f;
#pragma unroll
            for (int o = 0; o < O; o++) {
                float v = iou_pt(s_gt[o * 5 + 0], s_gt[o * 5 + 1], s_gt[o * 5 + 2], s_gt[o * 5 + 3],
                                 pb0, pb1, pb2, pb3);
                if (v > ov0) { ov0 = v; id0 = o; }
            }
            ov1 = -1.0f; id1 = 0;
            pb0 = pr1.x - pr1.z * 0.5f; pb1 = pr1.y - pr1.w * 0.5f;
            pb2 = pr1.x + pr1.z * 0.5f; pb3 = pr1.y + pr1.w * 0.5f;
#pragma unroll
            for (int o = 0; o < O; o++) {
                float v = iou_pt(s_gt[o * 5 + 0], s_gt[o * 5 + 1], s_gt[o * 5 + 2], s_gt[o * 5 + 3],
                                 pb0, pb1, pb2, pb3);
                if (v > ov1) { ov1 = v; id1 = o; }
            }
        }

        float mv0, mv1;
        size_t lp_base = (size_t)b * P;
        prior_body<0>(fs, s_gt, s_bp, pr0, p0, ov0, id0, loc_preds, lp_base, mv0, l_loc, l_ce, l_np);
        prior_body<1>(fs, s_gt, s_bp, pr1, p0, ov1, id1, loc_preds, lp_base, mv1, l_loc, l_ce, l_np);
        reinterpret_cast<float2*>(mine)[(size_t)b * HP + t] = make_float2(mv0, mv1);
    }

    // wave shuffle reductions (float partials -> double at wave leader)
    const int lane = tid & 63;
    const int wave = tid >> 6;
#pragma unroll
    for (int off = 32; off > 0; off >>= 1) {
        l_loc += __shfl_xor(l_loc, off, 64);
        l_ce  += __shfl_xor(l_ce, off, 64);
        l_np  += __shfl_xor(l_np, off, 64);
    }
    __shared__ double s_loc[4], s_ce[4];
    __shared__ int s_np[4];
    if (lane == 0) { s_loc[wave] = (double)l_loc; s_ce[wave] = (double)l_ce; s_np[wave] = l_np; }
    __syncthreads();
    if (tid == 0) {
        double t_loc = (s_loc[0] + s_loc[1]) + (s_loc[2] + s_loc[3]);
        double t_ce  = (s_ce[0] + s_ce[1]) + (s_ce[2] + s_ce[3]);
        int t_np = s_np[0] + s_np[1] + s_np[2] + s_np[3];
        atomicAdd(&acc[0], t_loc);
        atomicAdd(&acc[1], t_ce);
        atomicAdd(&num_pos[b], t_np);
        atomicAdd(total_pos, (u32)t_np);
    }
}

// Top-k sum via radix select (wave-parallel bin scan) + fused finalize.
__global__ void __launch_bounds__(1024) k_hardneg(const float* __restrict__ mine,
                                                  const int* __restrict__ num_pos,
                                                  const u32* __restrict__ total_pos,
                                                  double* __restrict__ acc,
                                                  u32* __restrict__ ticket,
                                                  float* __restrict__ out) {
    const int b = blockIdx.x;
    const int tid = threadIdx.x;
    __shared__ float s_mine[P];
    __shared__ u32 s_hist[256];
    __shared__ u32 s_sel[2];   // prefix, k_remaining
    __shared__ double s_red[16];

    const int tp = (int)*total_pos;
    const int np = num_pos[b];
    int k = 3 * np;
    int cap = P - tp - 1;
    if (cap < k) k = cap;

    if (k > 0) {
        for (int i = tid; i < P; i += 1024) s_mine[i] = mine[(size_t)b * P + i];
        if (tid == 0) { s_sel[0] = 0u; s_sel[1] = (u32)k; }
        __syncthreads();

        for (int shift = 24; shift >= 0; shift -= 8) {
            if (tid < 256) s_hist[tid] = 0u;
            __syncthreads();
            u32 prefix = s_sel[0];
            u32 kr = s_sel[1];
            u32 himask = (shift == 24) ? 0u : (0xFFFFFFFFu << (shift + 8));
            for (int i = tid; i < P; i += 1024) {
                u32 v = __float_as_uint(s_mine[i]);
                if ((v & himask) == prefix) atomicAdd(&s_hist[(v >> shift) & 255u], 1u);
            }
            __syncthreads();
            if (tid < 64) {   // wave 0: parallel descending-bin scan
                const int L = tid;
                const int btop = 255 - 4 * L;
                u32 h0 = s_hist[btop], h1 = s_hist[btop - 1], h2 = s_hist[btop - 2], h3 = s_hist[btop - 3];
                u32 g4 = h0 + h1 + h2 + h3;
                u32 x = g4;
#pragma unroll
                for (int off = 1; off < 64; off <<= 1) {
                    u32 v = __shfl_up(x, off, 64);
                    if (L >= off) x += v;
                }
                u32 excl = x - g4;   // count in bins above this lane's group
                if (excl < kr && excl + g4 >= kr) {   // crossing in this lane
                    u32 c = excl; int chosen = btop; u32 kloc = kr;
                    u32 hh0 = h0, hh1 = h1, hh2 = h2, hh3 = h3;
                    u32 nc;
                    nc = c + hh0; if (c < kr && nc >= kr) { chosen = btop;     kloc = kr - c; } c = nc;
                    nc = c + hh1; if (c < kr && nc >= kr) { chosen = btop - 1; kloc = kr - c; } c = nc;
                    nc = c + hh2; if (c < kr && nc >= kr) { chosen = btop - 2; kloc = kr - c; } c = nc;
                    nc = c + hh3; if (c < kr && nc >= kr) { chosen = btop - 3; kloc = kr - c; } c = nc;
                    s_sel[0] = prefix | ((u32)chosen << shift);
                    s_sel[1] = kloc;
                }
            }
            __syncthreads();
        }

        u32 tbits = s_sel[0];
        u32 kr = s_sel[1];
        float T = __uint_as_float(tbits);

        double sd = 0.0;
        for (int i = tid; i < P; i += 1024) {
            u32 v = __float_as_uint(s_mine[i]);
            if (v > tbits) sd += (double)s_mine[i];
        }
        const int lane = tid & 63;
        const int wave = tid >> 6;
#pragma unroll
        for (int off = 32; off > 0; off >>= 1) sd += __shfl_xor(sd, off, 64);
        if (lane == 0) s_red[wave] = sd;
        __syncthreads();
        if (tid == 0) {
            double tt = 0.0;
#pragma unroll
            for (int w = 0; w < 16; w++) tt += s_red[w];
            atomicAdd(&acc[2], tt + (double)kr * (double)T);
        }
    }

    // fused finalize: last block to arrive writes the outputs
    __threadfence();
    __syncthreads();
    if (tid == 0) {
        u32 old = atomicAdd(ticket, 1u);
        if (old == B - 1) {
            __threadfence();
            double a0 = atomicAdd(&acc[0], 0.0);
            double a1 = atomicAdd(&acc[1], 0.0);
            double a2 = atomicAdd(&acc[2], 0.0);
            double n = (double)tp;
            out[0] = (float)(a0 / n);
            out[1] = (float)((a1 + a2) / n);
        }
    }
}

extern "C" void kernel_launch(void* const* d_in, const int* in_sizes, int n_in,
                              void* d_out, int out_size, void* d_ws, size_t ws_size,
                              hipStream_t stream) {
    const float* loc_preds = (const float*)d_in[0];
    const float* scores    = (const float*)d_in[1];
    const float* gt        = (const float*)d_in[2];
    const float* priors    = (const float*)d_in[3];

    char* ws = (char*)d_ws;
    double* acc    = (double*)ws;           // [0,24)
    u32* total_pos = (u32*)(ws + 24);       // [24,28)
    u32* ticket    = (u32*)(ws + 28);       // [28,32)
    int* num_pos   = (int*)(ws + 32);       // [32,544)
    u64* bestkey   = (u64*)(ws + 544);      // [544,16928)

    // Precompute layout (needs ~10.08 MB): bestov f32[B*P], bestidx u8[B*P], mine f32[B*P]
    const bool pre = ws_size >= 10076300u;
    float* bestov; u8* bestidx; float* mine;
    if (pre) {
        bestov  = (float*)(ws + 16960);
        bestidx = (u8*)  (ws + 4487744);
        mine    = (float*)(ws + 5605440);
    } else {
        bestov = nullptr; bestidx = nullptr;
        mine   = (float*)(ws + 16960);
    }

    hipMemsetAsync(d_ws, 0, 16960, stream);

    k_pass1<<<dim3(8, B), dim3(256), 0, stream>>>(gt, priors, bestkey, bestov, bestidx);
    if (pre)
        k_pass2<true><<<dim3(18, B), dim3(256), 0, stream>>>(
            gt, priors, bestkey, loc_preds, scores, bestov, bestidx,
            mine, num_pos, total_pos, acc);
    else
        k_pass2<false><<<dim3(18, B), dim3(256), 0, stream>>>(
            gt, priors, bestkey, loc_preds, scores, bestov, bestidx,
            mine, num_pos, total_pos, acc);
    k_hardneg<<<dim3(B), dim3(1024), 0, stream>>>(mine, num_pos, total_pos, acc,
                                                  ticket, (float*)d_out);
}